// Round 15
// baseline (735.998 us; speedup 1.0000x reference)
//
#include <hip/hip_runtime.h>

#define NN 50000
#define NE 400000
#define NBATCH 8
#define DD 128
#define EGRID 1024
#define ETILES 6250

typedef unsigned short u16;
typedef __attribute__((ext_vector_type(8))) short bf16x8;
typedef __attribute__((ext_vector_type(8))) unsigned short u16x8;
typedef __attribute__((ext_vector_type(4))) unsigned short u16x4;
typedef __attribute__((ext_vector_type(4))) float f32x4;

__device__ __forceinline__ u16 f2bf(float f) {
  union { float f; unsigned u; } a; a.f = f;
  unsigned r = a.u + 0x7fffu + ((a.u >> 16) & 1u);
  return (u16)(r >> 16);
}

__device__ __forceinline__ void glds16(const void* g, void* l) {
  __builtin_amdgcn_global_load_lds(
      (const __attribute__((address_space(1))) unsigned*)g,
      (__attribute__((address_space(3))) unsigned*)l, 16, 0, 0);
}

// ---------------- merged prep kernel (R12 frozen) ----------------
__global__ __launch_bounds__(256) void prep_kernel(
    const float* __restrict__ eW1, const float* __restrict__ eW2, const float* __restrict__ eW3,
    const float* __restrict__ nW1, const float* __restrict__ nW2, const float* __restrict__ nW3,
    u16* __restrict__ wE1t, u16* __restrict__ wE2t, u16* __restrict__ wE3t,
    u16* __restrict__ wN1t, u16* __restrict__ wN2t, u16* __restrict__ wN3t,
    const float* __restrict__ x, u16* __restrict__ xbf,
    const float* __restrict__ u, u16* __restrict__ ubf,
    const int* __restrict__ batch, unsigned* __restrict__ ncnt,
    const int* __restrict__ edge_index, unsigned* __restrict__ ecnt,
    float* __restrict__ xout_zero)
{
  const int b = blockIdx.x;
  const int tid = threadIdx.x;

  if (b < 704) {
    const float* src; u16* dst; int K; int base;
    if (b < 256)      { src = eW1; dst = wE1t; K = 512; base = 0; }
    else if (b < 320) { src = eW2; dst = wE2t; K = 128; base = 256; }
    else if (b < 384) { src = eW3; dst = wE3t; K = 128; base = 320; }
    else if (b < 576) { src = nW1; dst = wN1t; K = 384; base = 384; }
    else if (b < 640) { src = nW2; dst = wN2t; K = 128; base = 576; }
    else              { src = nW3; dst = wN3t; K = 128; base = 640; }
    int idx = (b - base) * 256 + tid;
    if (idx < K * 128) {
      int k = idx >> 7, n = idx & 127;
      dst[((k >> 7) << 14) + (n << 7) + (k & 127)] = f2bf(src[idx]);
    }
    return;
  }
  if (b < 6954) {
    int i = (b - 704) * 256 + tid;
    f32x4 v = ((const f32x4*)x)[i];
    u16x4 o; o[0]=f2bf(v[0]); o[1]=f2bf(v[1]); o[2]=f2bf(v[2]); o[3]=f2bf(v[3]);
    ((u16x4*)xbf)[i] = o;
    return;
  }
  if (b == 6954) {
    f32x4 v = ((const f32x4*)u)[tid];
    u16x4 o; o[0]=f2bf(v[0]); o[1]=f2bf(v[1]); o[2]=f2bf(v[2]); o[3]=f2bf(v[3]);
    ((u16x4*)ubf)[tid] = o;
    return;
  }
  if (b < 7151) {
    __shared__ unsigned h[NBATCH];
    if (tid < NBATCH) h[tid] = 0;
    __syncthreads();
    int i = (b - 6955) * 256 + tid;
    if (i < NN) atomicAdd(&h[batch[i]], 1u);
    __syncthreads();
    if (tid < NBATCH) atomicAdd(&ncnt[tid], h[tid]);
    return;
  }
  if (b < 8714) {
    __shared__ unsigned h[NBATCH];
    if (tid < NBATCH) h[tid] = 0;
    __syncthreads();
    int e = (b - 7151) * 256 + tid;
    if (e < NE) atomicAdd(&h[batch[edge_index[e]]], 1u);
    __syncthreads();
    if (tid < NBATCH) atomicAdd(&ecnt[tid], h[tid]);
    return;
  }
  {
    int i = (b - 8714) * 256 + tid;
    f32x4 z = {0.f, 0.f, 0.f, 0.f};
    ((f32x4*)xout_zero)[i] = z;
  }
}

// ---------- combined final reduce: esumPart(EGRID slots)->esum, nsumPart(782)->nsum ----------
#define PR_SPAN 32
__global__ void finred_kernel(const float* __restrict__ esumPart, float* __restrict__ esum,
                              const float* __restrict__ nsumPart, float* __restrict__ nsum,
                              int nNode) {
  const int EB = (EGRID + PR_SPAN - 1) / PR_SPAN;   // 32
  const float* part; float* out; int nslot; int bb;
  if (blockIdx.x < EB) { part = esumPart; out = esum; nslot = EGRID; bb = blockIdx.x; }
  else                 { part = nsumPart; out = nsum; nslot = nNode; bb = blockIdx.x - EB; }
  int b0 = bb * PR_SPAN;
  int i = threadIdx.x;
  int bend = b0 + PR_SPAN; if (bend > nslot) bend = nslot;
  float s0 = 0.f, s1 = 0.f, s2 = 0.f, s3 = 0.f;
  for (int b = b0; b < bend; ++b) {
    const float* p = part + (size_t)b * 1024;
    s0 += p[i]; s1 += p[256 + i]; s2 += p[512 + i]; s3 += p[768 + i];
  }
  atomicAdd(&out[i], s0);
  atomicAdd(&out[256 + i], s1);
  atomicAdd(&out[512 + i], s2);
  atomicAdd(&out[768 + i], s3);
}

// ---------------- Edge MLP: PERSISTENT blocks (1 generation), R12 rhythm per tile ----------------
__global__ __launch_bounds__(256, 4) void edge_kernel(
    const u16* __restrict__ xbf,
    const float* __restrict__ ea_f32, const u16* __restrict__ ubf,
    const int* __restrict__ edge_index, const int* __restrict__ batch,
    const u16* __restrict__ w1, const u16* __restrict__ w2, const u16* __restrict__ w3,
    const float* __restrict__ b1, const float* __restrict__ b2, const float* __restrict__ b3,
    float* __restrict__ edge_out, float* agg, float* __restrict__ esumPart)
{
  __shared__ u16 As[2][64 * 128];       // 32 KB double buffer
  __shared__ float red[NBATCH * 128];
  __shared__ int rows_s[2][64], cols_s[2][64], ebat_s[2][64];

  const int tid  = threadIdx.x;
  const int lane = tid & 63;
  const int wave = tid >> 6;
  const int wc   = wave;                // 4 waves tile N=128 as 4 x 32 cols
  const int lr   = lane & 15;
  const int lkb  = lane >> 4;
  const int bid  = blockIdx.x;
  const int ntiles = (ETILES - bid + EGRID - 1) / EGRID;

  for (int i = tid; i < NBATCH * 128; i += 256) red[i] = 0.f;

  f32x4 acc[4][2];
#pragma unroll
  for (int m = 0; m < 4; ++m)
#pragma unroll
    for (int n = 0; n < 2; ++n) { acc[m][n][0]=0.f; acc[m][n][1]=0.f; acc[m][n][2]=0.f; acc[m][n][3]=0.f; }

  auto stage = [&](int buf, int c, int p, int e0) {
    if (c == 2) {
      // edge_attr fp32: reg-stage + cvt + swizzled ds_write (coalesced 512B/row)
#pragma unroll
      for (int j = 0; j < 4; ++j) {
        int idx = j * 64 + lane;
        int rr = wave * 16 + (idx >> 4);
        int k  = idx & 15;
        const float* p4 = ea_f32 + (size_t)(e0 + rr) * DD + k * 8;
        f32x4 a = *(const f32x4*)p4;
        f32x4 b = *(const f32x4*)(p4 + 4);
        u16x8 v;
        v[0]=f2bf(a[0]); v[1]=f2bf(a[1]); v[2]=f2bf(a[2]); v[3]=f2bf(a[3]);
        v[4]=f2bf(b[0]); v[5]=f2bf(b[1]); v[6]=f2bf(b[2]); v[7]=f2bf(b[3]);
        *(u16x8*)&As[buf][rr * 128 + ((k ^ (rr & 7)) << 3)] = v;
      }
      return;
    }
#pragma unroll
    for (int i = 0; i < 4; ++i) {
      int rr = wave * 16 + i * 4 + (lane >> 4);
      const u16* rp;
      if (c == 0)      rp = xbf + (size_t)rows_s[p][rr] * DD;
      else if (c == 1) rp = xbf + (size_t)cols_s[p][rr] * DD;
      else             rp = ubf + (size_t)ebat_s[p][rr] * DD;
      const u16* src = rp + (((lane & 15) ^ (rr & 7)) << 3);  // inverse-swizzled source
      u16* dst = &As[buf][(wave * 16 + i * 4) * 128];         // linear wave-uniform dest
      glds16(src, dst);
    }
  };

  auto compute = [&](const u16* AsBuf, const u16* wsrc) {
#pragma unroll
    for (int kk = 0; kk < 4; ++kk) {
      const int k0 = kk * 32 + lkb * 8;
      bf16x8 af[4], bfv[2];
#pragma unroll
      for (int m = 0; m < 4; ++m) {
        int g = m * 16 + lr;
        int slot = kk * 4 + lkb;
        af[m] = *(const bf16x8*)(AsBuf + g * 128 + ((slot ^ (g & 7)) << 3));
      }
#pragma unroll
      for (int n = 0; n < 2; ++n)
        bfv[n] = *(const bf16x8*)(wsrc + ((wc * 32 + n * 16 + lr) << 7) + k0);
#pragma unroll
      for (int m = 0; m < 4; ++m)
#pragma unroll
        for (int n = 0; n < 2; ++n)
          acc[m][n] = __builtin_amdgcn_mfma_f32_16x16x32_bf16(af[m], bfv[n], acc[m][n], 0, 0, 0);
    }
  };

  auto epi_relu = [&](u16* HsBuf, const float* bias) {
#pragma unroll
    for (int n = 0; n < 2; ++n) {
      int colg = wc * 32 + n * 16 + lr;
      float bv = bias[colg];
      int slot = colg >> 3;
#pragma unroll
      for (int m = 0; m < 4; ++m)
#pragma unroll
        for (int r = 0; r < 4; ++r) {
          int rowg = m * 16 + lkb * 4 + r;
          float v = fmaxf(acc[m][n][r] + bv, 0.f);
          HsBuf[rowg * 128 + ((slot ^ (rowg & 7)) << 3) + (colg & 7)] = f2bf(v);
          acc[m][n][r] = 0.f;
        }
    }
  };

  // prologue: tile-0 indices -> slot 0, then stage c0 -> As[0]
  if (tid < 64) {
    int e0 = bid * 64;
    int r = edge_index[e0 + tid];
    int c = edge_index[NE + e0 + tid];
    rows_s[0][tid] = r; cols_s[0][tid] = c; ebat_s[0][tid] = batch[r];
  }
  __syncthreads();
  stage(0, 0, 0, bid * 64);
  __syncthreads();

  for (int k = 0; k < ntiles; ++k) {
    const int p  = k & 1;
    const int e0 = (bid + k * EGRID) * 64;
    const bool hasNext = (k + 1 < ntiles);
    const int e0n = hasNext ? (bid + (k + 1) * EGRID) * 64 : e0;

    // prefetch next tile's indices into the other parity slot (read many phases later)
    if (hasNext && tid < 64) {
      int r = edge_index[e0n + tid];
      int c = edge_index[NE + e0n + tid];
      rows_s[p ^ 1][tid] = r; cols_s[p ^ 1][tid] = c; ebat_s[p ^ 1][tid] = batch[r];
    }

    stage(1, 1, p, e0); compute(As[0], w1);                __syncthreads();
    stage(0, 2, p, e0); compute(As[1], w1 + (1 << 14));    __syncthreads();
    stage(1, 3, p, e0); compute(As[0], w1 + (2 << 14));    __syncthreads();
                        compute(As[1], w1 + (3 << 14));
    epi_relu(As[0], b1);
    __syncthreads();
    compute(As[0], w2);
    __syncthreads();
    epi_relu(As[1], b2);
    __syncthreads();
    // prefetch next tile's c0 into As[0] (safe: As[0] last read before previous barrier)
    if (hasNext) stage(0, 0, p ^ 1, e0n);
    compute(As[1], w3);

    // epilogue: edge_out stores + agg scatter atomics + per-graph red (LDS, accumulated across tiles)
#pragma unroll
    for (int n = 0; n < 2; ++n) {
      int colg = wc * 32 + n * 16 + lr;
      float bias = b3[colg];
#pragma unroll
      for (int m = 0; m < 4; ++m)
#pragma unroll
        for (int r = 0; r < 4; ++r) {
          int rowg = m * 16 + lkb * 4 + r;
          float v = acc[m][n][r] + bias;
          edge_out[(size_t)(e0 + rowg) * DD + colg] = v;
          atomicAdd(&agg[(size_t)cols_s[p][rowg] * DD + colg], v);
          atomicAdd(&red[ebat_s[p][rowg] * 128 + colg], v);
          acc[m][n][r] = 0.f;
        }
    }
    __syncthreads();   // drains c0 prefetch + red done + next-idx visible
  }

  // single flush of per-block esum partial
  for (int i = tid; i < NBATCH * 128; i += 256)
    esumPart[((size_t)bid << 10) + i] = red[i];
}

// ---------------- Node MLP (R12 frozen): 64-node tile, agg in x_out region ----------------
__global__ __launch_bounds__(256, 4) void node_kernel(
    const u16* __restrict__ xbf, float* aggx /* agg in, x_out out (same region) */,
    const u16* __restrict__ ubf, const int* __restrict__ batch,
    const u16* __restrict__ w1, const u16* __restrict__ w2, const u16* __restrict__ w3,
    const float* __restrict__ b1, const float* __restrict__ b2, const float* __restrict__ b3,
    float* __restrict__ nsumPart)
{
  __shared__ u16 As[2][64 * 128];
  __shared__ float red[NBATCH][128];
  __shared__ int nbat_s[64];

  const int tid  = threadIdx.x;
  const int lane = tid & 63;
  const int wave = tid >> 6;
  const int wc   = wave;
  const int lr   = lane & 15;
  const int lkb  = lane >> 4;
  const int n0   = blockIdx.x * 64;

  if (tid < 64) {
    int node = n0 + tid;
    nbat_s[tid] = (node < NN) ? batch[node] : 0;
  }
  for (int i = tid; i < NBATCH * 128; i += 256) (&red[0][0])[i] = 0.f;

  f32x4 acc[4][2];
#pragma unroll
  for (int m = 0; m < 4; ++m)
#pragma unroll
    for (int n = 0; n < 2; ++n) { acc[m][n][0]=0.f; acc[m][n][1]=0.f; acc[m][n][2]=0.f; acc[m][n][3]=0.f; }

  __syncthreads();

  auto stage_bf = [&](int buf, int c) {   // c==0: xbf rows ; c==2: ubf rows
#pragma unroll
    for (int i = 0; i < 4; ++i) {
      int rr = wave * 16 + i * 4 + (lane >> 4);
      int node = n0 + rr; if (node >= NN) node = 0;
      const u16* rp = (c == 0) ? (xbf + (size_t)node * DD)
                               : (ubf + (size_t)nbat_s[rr] * DD);
      const u16* src = rp + (((lane & 15) ^ (rr & 7)) << 3);
      u16* dst = &As[buf][(wave * 16 + i * 4) * 128];
      glds16(src, dst);
    }
  };

  auto stage_agg = [&](int buf) {
#pragma unroll
    for (int j = 0; j < 4; ++j) {
      int idx = j * 64 + lane;
      int rr = wave * 16 + (idx >> 4);
      int k  = idx & 15;
      int node = n0 + rr; if (node >= NN) node = 0;
      const float* p = aggx + (size_t)node * DD + k * 8;
      f32x4 a = *(const f32x4*)p;
      f32x4 b = *(const f32x4*)(p + 4);
      u16x8 v;
      v[0]=f2bf(a[0]); v[1]=f2bf(a[1]); v[2]=f2bf(a[2]); v[3]=f2bf(a[3]);
      v[4]=f2bf(b[0]); v[5]=f2bf(b[1]); v[6]=f2bf(b[2]); v[7]=f2bf(b[3]);
      *(u16x8*)&As[buf][rr * 128 + ((k ^ (rr & 7)) << 3)] = v;
    }
  };

  auto compute = [&](const u16* AsBuf, const u16* wsrc) {
#pragma unroll
    for (int kk = 0; kk < 4; ++kk) {
      const int k0 = kk * 32 + lkb * 8;
      bf16x8 af[4], bfv[2];
#pragma unroll
      for (int m = 0; m < 4; ++m) {
        int g = m * 16 + lr;
        int slot = kk * 4 + lkb;
        af[m] = *(const bf16x8*)(AsBuf + g * 128 + ((slot ^ (g & 7)) << 3));
      }
#pragma unroll
      for (int n = 0; n < 2; ++n)
        bfv[n] = *(const bf16x8*)(wsrc + ((wc * 32 + n * 16 + lr) << 7) + k0);
#pragma unroll
      for (int m = 0; m < 4; ++m)
#pragma unroll
        for (int n = 0; n < 2; ++n)
          acc[m][n] = __builtin_amdgcn_mfma_f32_16x16x32_bf16(af[m], bfv[n], acc[m][n], 0, 0, 0);
    }
  };

  auto epi_relu = [&](u16* HsBuf, const float* bias) {
#pragma unroll
    for (int n = 0; n < 2; ++n) {
      int colg = wc * 32 + n * 16 + lr;
      float bv = bias[colg];
      int slot = colg >> 3;
#pragma unroll
      for (int m = 0; m < 4; ++m)
#pragma unroll
        for (int r = 0; r < 4; ++r) {
          int rowg = m * 16 + lkb * 4 + r;
          float v = fmaxf(acc[m][n][r] + bv, 0.f);
          HsBuf[rowg * 128 + ((slot ^ (rowg & 7)) << 3) + (colg & 7)] = f2bf(v);
          acc[m][n][r] = 0.f;
        }
    }
  };

  stage_bf(0, 0);
  __syncthreads();
  stage_agg(1);   compute(As[0], w1);               __syncthreads();
  stage_bf(0, 2); compute(As[1], w1 + (1 << 14));   __syncthreads();
                  compute(As[0], w1 + (2 << 14));
  epi_relu(As[1], b1);
  __syncthreads();
  compute(As[1], w2);
  __syncthreads();
  epi_relu(As[0], b2);
  __syncthreads();
  compute(As[0], w3);

#pragma unroll
  for (int n = 0; n < 2; ++n) {
    int colg = wc * 32 + n * 16 + lr;
    float bias = b3[colg];
#pragma unroll
    for (int m = 0; m < 4; ++m)
#pragma unroll
      for (int r = 0; r < 4; ++r) {
        int rowg = m * 16 + lkb * 4 + r;
        int node = n0 + rowg;
        if (node < NN) {
          float v = acc[m][n][r] + bias;
          aggx[(size_t)node * DD + colg] = v;
          atomicAdd(&red[nbat_s[rowg]][colg], v);
        }
      }
  }
  __syncthreads();
  for (int i = tid; i < NBATCH * 128; i += 256)
    nsumPart[((size_t)blockIdx.x << 10) + i] = (&red[0][0])[i];
}

// ---------------- Global MLP (fp32, tiny) ----------------
__global__ void global_kernel(
    const float* __restrict__ u,
    const float* __restrict__ nsum, const unsigned* __restrict__ ncnt,
    const float* __restrict__ esum, const unsigned* __restrict__ ecnt,
    const float* __restrict__ gW1, const float* __restrict__ gb1,
    const float* __restrict__ gW2, const float* __restrict__ gb2,
    const float* __restrict__ gW3, const float* __restrict__ gb3,
    float* __restrict__ u_out)
{
  __shared__ float gin[NBATCH][384];
  __shared__ float h1[NBATCH][128];
  __shared__ float h2[NBATCH][128];
  int tid = threadIdx.x;
  for (int i = tid; i < NBATCH * 128; i += 256) {
    int r = i >> 7, c = i & 127;
    float nc = (float)(ncnt[r] < 1u ? 1u : ncnt[r]);
    float ec = (float)(ecnt[r] < 1u ? 1u : ecnt[r]);
    gin[r][c] = u[i];
    gin[r][128 + c] = nsum[i] / nc;
    gin[r][256 + c] = esum[i] / ec;
  }
  __syncthreads();
  for (int o = tid; o < NBATCH * 128; o += 256) {
    int r = o >> 7, n = o & 127;
    float s = gb1[n];
    for (int k = 0; k < 384; ++k) s += gin[r][k] * gW1[k * 128 + n];
    h1[r][n] = fmaxf(s, 0.f);
  }
  __syncthreads();
  for (int o = tid; o < NBATCH * 128; o += 256) {
    int r = o >> 7, n = o & 127;
    float s = gb2[n];
    for (int k = 0; k < 128; ++k) s += h1[r][k] * gW2[k * 128 + n];
    h2[r][n] = fmaxf(s, 0.f);
  }
  __syncthreads();
  for (int o = tid; o < NBATCH * 128; o += 256) {
    int r = o >> 7, n = o & 127;
    float s = gb3[n];
    for (int k = 0; k < 128; ++k) s += h2[r][k] * gW3[k * 128 + n];
    u_out[o] = s;
  }
}

extern "C" void kernel_launch(void* const* d_in, const int* in_sizes, int n_in,
                              void* d_out, int out_size, void* d_ws, size_t ws_size,
                              hipStream_t stream) {
  const float* x          = (const float*)d_in[0];
  const int*   edge_index = (const int*)d_in[1];
  const float* edge_attr  = (const float*)d_in[2];
  const float* u          = (const float*)d_in[3];
  const int*   batch      = (const int*)d_in[4];
  const float* eW1 = (const float*)d_in[5];  const float* eb1 = (const float*)d_in[6];
  const float* eW2 = (const float*)d_in[7];  const float* eb2 = (const float*)d_in[8];
  const float* eW3 = (const float*)d_in[9];  const float* eb3 = (const float*)d_in[10];
  const float* nW1 = (const float*)d_in[11]; const float* nb1 = (const float*)d_in[12];
  const float* nW2 = (const float*)d_in[13]; const float* nb2 = (const float*)d_in[14];
  const float* nW3 = (const float*)d_in[15]; const float* nb3 = (const float*)d_in[16];
  const float* gW1 = (const float*)d_in[17]; const float* gb1 = (const float*)d_in[18];
  const float* gW2 = (const float*)d_in[19]; const float* gb2 = (const float*)d_in[20];
  const float* gW3 = (const float*)d_in[21]; const float* gb3 = (const float*)d_in[22];

  float* out      = (float*)d_out;
  float* xout_agg = out;                                  // [NN][128]: agg then x_out
  float* edge_out = out + (size_t)NN * DD;                // [NE][128]
  float* u_out    = out + (size_t)(NN + NE) * DD;         // [8][128]

  char* ws = (char*)d_ws;
  u16* wE1t = (u16*)(ws + 0);         // 131072
  u16* wE2t = (u16*)(ws + 131072);    // 32768
  u16* wE3t = (u16*)(ws + 163840);    // 32768
  u16* wN1t = (u16*)(ws + 196608);    // 98304
  u16* wN2t = (u16*)(ws + 294912);    // 32768
  u16* wN3t = (u16*)(ws + 327680);    // 32768
  float*    esum = (float*)(ws + 360448);     // 4096
  float*    nsum = (float*)(ws + 364544);     // 4096
  unsigned* ecnt = (unsigned*)(ws + 368640);  // 32
  unsigned* ncnt = (unsigned*)(ws + 368672);  // 32
  u16*      ubf  = (u16*)(ws + 369664);       // 2048
  u16*      xbf  = (u16*)(ws + 393216);       // 12,800,000 -> ends 13,193,216
  float* esumPart = (float*)(ws + 13193216);  // EGRID*4096 = 4,194,304 -> 17,387,520
  float* nsumPart = (float*)(ws + 17387520);  // 782*4096  = 3,203,072 -> ends 20,590,592

  const int NODE_BLOCKS = (NN + 63) / 64;     // 782

  // zero esum/nsum/ecnt/ncnt (must precede prep's histograms)
  hipMemsetAsync(ws + 360448, 0, 8288, stream);

  prep_kernel<<<14964, 256, 0, stream>>>(
      eW1, eW2, eW3, nW1, nW2, nW3,
      wE1t, wE2t, wE3t, wN1t, wN2t, wN3t,
      x, xbf, u, ubf, batch, ncnt, edge_index, ecnt,
      xout_agg);

  edge_kernel<<<EGRID, 256, 0, stream>>>(
      xbf, edge_attr, ubf, edge_index, batch,
      wE1t, wE2t, wE3t, eb1, eb2, eb3,
      edge_out, xout_agg, esumPart);

  node_kernel<<<NODE_BLOCKS, 256, 0, stream>>>(
      xbf, xout_agg, ubf, batch,
      wN1t, wN2t, wN3t, nb1, nb2, nb3,
      nsumPart);

  finred_kernel<<<(EGRID + PR_SPAN - 1) / PR_SPAN + (NODE_BLOCKS + PR_SPAN - 1) / PR_SPAN,
                  256, 0, stream>>>(esumPart, esum, nsumPart, nsum, NODE_BLOCKS);

  global_kernel<<<1, 256, 0, stream>>>(
      u, nsum, ncnt, esum, ecnt,
      gW1, gb1, gW2, gb2, gW3, gb3, u_out);
}

// Round 16
// 559.332 us; speedup vs baseline: 1.3159x; 1.3159x over previous
//
#include <hip/hip_runtime.h>

#define NN 50000
#define NE 400000
#define NBATCH 8
#define DD 128

typedef unsigned short u16;
typedef __attribute__((ext_vector_type(8))) short bf16x8;
typedef __attribute__((ext_vector_type(8))) unsigned short u16x8;
typedef __attribute__((ext_vector_type(4))) unsigned short u16x4;
typedef __attribute__((ext_vector_type(4))) float f32x4;

__device__ __forceinline__ u16 f2bf(float f) {
  union { float f; unsigned u; } a; a.f = f;
  unsigned r = a.u + 0x7fffu + ((a.u >> 16) & 1u);
  return (u16)(r >> 16);
}

__device__ __forceinline__ void glds16(const void* g, void* l) {
  __builtin_amdgcn_global_load_lds(
      (const __attribute__((address_space(1))) unsigned*)g,
      (__attribute__((address_space(3))) unsigned*)l, 16, 0, 0);
}

// ---------------- merged prep kernel: all conversions + histograms + x_out zero ----------------
// block ranges:
//   [0,256)      wconv eW1 (K=512)     [256,320)  wconv eW2     [320,384) wconv eW3
//   [384,576)    wconv nW1 (K=384)     [576,640)  wconv nW2     [640,704) wconv nW3
//   [704,6954)   xconv x               [6954]     xconv u
//   [6955,7151)  nhist                 [7151,8714) ecnt
//   [8714,14964) zero x_out region (agg accumulator)
__global__ __launch_bounds__(256) void prep_kernel(
    const float* __restrict__ eW1, const float* __restrict__ eW2, const float* __restrict__ eW3,
    const float* __restrict__ nW1, const float* __restrict__ nW2, const float* __restrict__ nW3,
    u16* __restrict__ wE1t, u16* __restrict__ wE2t, u16* __restrict__ wE3t,
    u16* __restrict__ wN1t, u16* __restrict__ wN2t, u16* __restrict__ wN3t,
    const float* __restrict__ x, u16* __restrict__ xbf,
    const float* __restrict__ u, u16* __restrict__ ubf,
    const int* __restrict__ batch, unsigned* __restrict__ ncnt,
    const int* __restrict__ edge_index, unsigned* __restrict__ ecnt,
    float* __restrict__ xout_zero)
{
  const int b = blockIdx.x;
  const int tid = threadIdx.x;

  if (b < 704) {
    // weight convert+transpose
    const float* src; u16* dst; int K; int base;
    if (b < 256)      { src = eW1; dst = wE1t; K = 512; base = 0; }
    else if (b < 320) { src = eW2; dst = wE2t; K = 128; base = 256; }
    else if (b < 384) { src = eW3; dst = wE3t; K = 128; base = 320; }
    else if (b < 576) { src = nW1; dst = wN1t; K = 384; base = 384; }
    else if (b < 640) { src = nW2; dst = wN2t; K = 128; base = 576; }
    else              { src = nW3; dst = wN3t; K = 128; base = 640; }
    int idx = (b - base) * 256 + tid;
    if (idx < K * 128) {
      int k = idx >> 7, n = idx & 127;
      dst[((k >> 7) << 14) + (n << 7) + (k & 127)] = f2bf(src[idx]);
    }
    return;
  }
  if (b < 6954) {
    int i = (b - 704) * 256 + tid;   // < 1,600,000 exactly
    f32x4 v = ((const f32x4*)x)[i];
    u16x4 o; o[0]=f2bf(v[0]); o[1]=f2bf(v[1]); o[2]=f2bf(v[2]); o[3]=f2bf(v[3]);
    ((u16x4*)xbf)[i] = o;
    return;
  }
  if (b == 6954) {
    f32x4 v = ((const f32x4*)u)[tid];     // 256 == NBATCH*DD/4
    u16x4 o; o[0]=f2bf(v[0]); o[1]=f2bf(v[1]); o[2]=f2bf(v[2]); o[3]=f2bf(v[3]);
    ((u16x4*)ubf)[tid] = o;
    return;
  }
  if (b < 7151) {
    __shared__ unsigned h[NBATCH];
    if (tid < NBATCH) h[tid] = 0;
    __syncthreads();
    int i = (b - 6955) * 256 + tid;
    if (i < NN) atomicAdd(&h[batch[i]], 1u);
    __syncthreads();
    if (tid < NBATCH) atomicAdd(&ncnt[tid], h[tid]);
    return;
  }
  if (b < 8714) {
    __shared__ unsigned h[NBATCH];
    if (tid < NBATCH) h[tid] = 0;
    __syncthreads();
    int e = (b - 7151) * 256 + tid;
    if (e < NE) atomicAdd(&h[batch[edge_index[e]]], 1u);
    __syncthreads();
    if (tid < NBATCH) atomicAdd(&ecnt[tid], h[tid]);
    return;
  }
  {
    // zero x_out region: 6250 blocks x 1024 floats
    int i = (b - 8714) * 256 + tid;    // f32x4 index, < 1,600,000
    f32x4 z = {0.f, 0.f, 0.f, 0.f};
    ((f32x4*)xout_zero)[i] = z;
  }
}

// ---------- parallel partial reduce: [nslot][1024] -> out[1024] (atomic merge; out pre-zeroed) ----------
#define PR_SPAN 32
__global__ void partred_kernel(const float* __restrict__ part, float* __restrict__ out, int nslot) {
  int b0 = blockIdx.x * PR_SPAN;
  int i = threadIdx.x;
  int bend = b0 + PR_SPAN; if (bend > nslot) bend = nslot;
  float s0 = 0.f, s1 = 0.f, s2 = 0.f, s3 = 0.f;
  for (int b = b0; b < bend; ++b) {
    const float* p = part + (size_t)b * 1024;
    s0 += p[i]; s1 += p[256 + i]; s2 += p[512 + i]; s3 += p[768 + i];
  }
  atomicAdd(&out[i], s0);
  atomicAdd(&out[256 + i], s1);
  atomicAdd(&out[512 + i], s2);
  atomicAdd(&out[768 + i], s3);
}

// ---------------- Edge MLP: 64-edge tile, 32KB dbuf, 4 blk/CU ----------------
// R11 structure + agg scatter atomics (R10-measured ~free); esum via plain per-block stores.
__global__ __launch_bounds__(256, 4) void edge_kernel(
    const u16* __restrict__ xbf,
    const float* __restrict__ ea_f32, const u16* __restrict__ ubf,
    const int* __restrict__ edge_index, const int* __restrict__ batch,
    const u16* __restrict__ w1, const u16* __restrict__ w2, const u16* __restrict__ w3,
    const float* __restrict__ b1, const float* __restrict__ b2, const float* __restrict__ b3,
    float* __restrict__ edge_out, float* agg, float* __restrict__ esumPart)
{
  __shared__ u16 As[2][64 * 128];       // 32 KB double buffer
  __shared__ float red[NBATCH][128];
  __shared__ int rows_s[64], cols_s[64], ebat_s[64];

  const int tid  = threadIdx.x;
  const int lane = tid & 63;
  const int wave = tid >> 6;
  const int wc   = wave;                // 4 waves tile N=128 as 4 x 32 cols
  const int lr   = lane & 15;
  const int lkb  = lane >> 4;
  const int e0   = blockIdx.x * 64;

  if (tid < 64) {
    int r = edge_index[e0 + tid];
    int c = edge_index[NE + e0 + tid];
    rows_s[tid] = r; cols_s[tid] = c;
    ebat_s[tid] = batch[r];
  }
  for (int i = tid; i < NBATCH * 128; i += 256) (&red[0][0])[i] = 0.f;

  f32x4 acc[4][2];
#pragma unroll
  for (int m = 0; m < 4; ++m)
#pragma unroll
    for (int n = 0; n < 2; ++n) { acc[m][n][0]=0.f; acc[m][n][1]=0.f; acc[m][n][2]=0.f; acc[m][n][3]=0.f; }

  __syncthreads();  // indices visible

  auto stage = [&](int buf, int c) {
    if (c == 2) {
      // edge_attr fp32: reg-stage + cvt + swizzled ds_write (coalesced 512B/row)
#pragma unroll
      for (int j = 0; j < 4; ++j) {
        int idx = j * 64 + lane;
        int rr = wave * 16 + (idx >> 4);
        int k  = idx & 15;
        const float* p = ea_f32 + (size_t)(e0 + rr) * DD + k * 8;
        f32x4 a = *(const f32x4*)p;
        f32x4 b = *(const f32x4*)(p + 4);
        u16x8 v;
        v[0]=f2bf(a[0]); v[1]=f2bf(a[1]); v[2]=f2bf(a[2]); v[3]=f2bf(a[3]);
        v[4]=f2bf(b[0]); v[5]=f2bf(b[1]); v[6]=f2bf(b[2]); v[7]=f2bf(b[3]);
        *(u16x8*)&As[buf][rr * 128 + ((k ^ (rr & 7)) << 3)] = v;
      }
      return;
    }
#pragma unroll
    for (int i = 0; i < 4; ++i) {
      int rr = wave * 16 + i * 4 + (lane >> 4);
      const u16* rp;
      if (c == 0)      rp = xbf + (size_t)rows_s[rr] * DD;
      else if (c == 1) rp = xbf + (size_t)cols_s[rr] * DD;
      else             rp = ubf + (size_t)ebat_s[rr] * DD;
      const u16* src = rp + (((lane & 15) ^ (rr & 7)) << 3);  // inverse-swizzled source
      u16* dst = &As[buf][(wave * 16 + i * 4) * 128];         // linear wave-uniform dest
      glds16(src, dst);
    }
  };

  auto compute = [&](const u16* AsBuf, const u16* wsrc) {
#pragma unroll
    for (int kk = 0; kk < 4; ++kk) {
      const int k0 = kk * 32 + lkb * 8;
      bf16x8 af[4], bfv[2];
#pragma unroll
      for (int m = 0; m < 4; ++m) {
        int g = m * 16 + lr;
        int slot = kk * 4 + lkb;
        af[m] = *(const bf16x8*)(AsBuf + g * 128 + ((slot ^ (g & 7)) << 3));
      }
#pragma unroll
      for (int n = 0; n < 2; ++n)
        bfv[n] = *(const bf16x8*)(wsrc + ((wc * 32 + n * 16 + lr) << 7) + k0);
#pragma unroll
      for (int m = 0; m < 4; ++m)
#pragma unroll
        for (int n = 0; n < 2; ++n)
          acc[m][n] = __builtin_amdgcn_mfma_f32_16x16x32_bf16(af[m], bfv[n], acc[m][n], 0, 0, 0);
    }
  };

  auto epi_relu = [&](u16* HsBuf, const float* bias) {
#pragma unroll
    for (int n = 0; n < 2; ++n) {
      int colg = wc * 32 + n * 16 + lr;
      float bv = bias[colg];
      int slot = colg >> 3;
#pragma unroll
      for (int m = 0; m < 4; ++m)
#pragma unroll
        for (int r = 0; r < 4; ++r) {
          int rowg = m * 16 + lkb * 4 + r;
          float v = fmaxf(acc[m][n][r] + bv, 0.f);
          HsBuf[rowg * 128 + ((slot ^ (rowg & 7)) << 3) + (colg & 7)] = f2bf(v);
          acc[m][n][r] = 0.f;
        }
    }
  };

  // ---- layer 1: 4 chunks, 2-phase (stage next, compute current, barrier)
  stage(0, 0);
  __syncthreads();
  stage(1, 1); compute(As[0], w1);                __syncthreads();
  stage(0, 2); compute(As[1], w1 + (1 << 14));    __syncthreads();
  stage(1, 3); compute(As[0], w1 + (2 << 14));    __syncthreads();
               compute(As[1], w1 + (3 << 14));
  epi_relu(As[0], b1);
  __syncthreads();
  compute(As[0], w2);
  __syncthreads();
  epi_relu(As[1], b2);
  __syncthreads();
  compute(As[1], w3);

  // epilogue 3: edge_out stores + agg scatter atomics + per-graph red (LDS)
#pragma unroll
  for (int n = 0; n < 2; ++n) {
    int colg = wc * 32 + n * 16 + lr;
    float bias = b3[colg];
#pragma unroll
    for (int m = 0; m < 4; ++m)
#pragma unroll
      for (int r = 0; r < 4; ++r) {
        int rowg = m * 16 + lkb * 4 + r;
        float v = acc[m][n][r] + bias;
        edge_out[(size_t)(e0 + rowg) * DD + colg] = v;
        atomicAdd(&agg[(size_t)cols_s[rowg] * DD + colg], v);
        atomicAdd(&red[ebat_s[rowg]][colg], v);
      }
  }
  __syncthreads();
  // plain-store flush of per-block partial (no global atomics)
  for (int i = tid; i < NBATCH * 128; i += 256)
    esumPart[((size_t)blockIdx.x << 10) + i] = (&red[0][0])[i];
}

// ---------------- Node MLP: 64-node tile, agg read from x_out region, overwrite in place ----------------
__global__ __launch_bounds__(256, 4) void node_kernel(
    const u16* __restrict__ xbf, float* aggx /* agg in, x_out out (same region) */,
    const u16* __restrict__ ubf, const int* __restrict__ batch,
    const u16* __restrict__ w1, const u16* __restrict__ w2, const u16* __restrict__ w3,
    const float* __restrict__ b1, const float* __restrict__ b2, const float* __restrict__ b3,
    float* __restrict__ nsumPart)
{
  __shared__ u16 As[2][64 * 128];
  __shared__ float red[NBATCH][128];
  __shared__ int nbat_s[64];

  const int tid  = threadIdx.x;
  const int lane = tid & 63;
  const int wave = tid >> 6;
  const int wc   = wave;
  const int lr   = lane & 15;
  const int lkb  = lane >> 4;
  const int n0   = blockIdx.x * 64;

  if (tid < 64) {
    int node = n0 + tid;
    nbat_s[tid] = (node < NN) ? batch[node] : 0;
  }
  for (int i = tid; i < NBATCH * 128; i += 256) (&red[0][0])[i] = 0.f;

  f32x4 acc[4][2];
#pragma unroll
  for (int m = 0; m < 4; ++m)
#pragma unroll
    for (int n = 0; n < 2; ++n) { acc[m][n][0]=0.f; acc[m][n][1]=0.f; acc[m][n][2]=0.f; acc[m][n][3]=0.f; }

  __syncthreads();

  auto stage_bf = [&](int buf, int c) {   // c==0: xbf rows ; c==2: ubf rows
#pragma unroll
    for (int i = 0; i < 4; ++i) {
      int rr = wave * 16 + i * 4 + (lane >> 4);
      int node = n0 + rr; if (node >= NN) node = 0;
      const u16* rp = (c == 0) ? (xbf + (size_t)node * DD)
                               : (ubf + (size_t)nbat_s[rr] * DD);
      const u16* src = rp + (((lane & 15) ^ (rr & 7)) << 3);
      u16* dst = &As[buf][(wave * 16 + i * 4) * 128];
      glds16(src, dst);
    }
  };

  auto stage_agg = [&](int buf) {
#pragma unroll
    for (int j = 0; j < 4; ++j) {
      int idx = j * 64 + lane;
      int rr = wave * 16 + (idx >> 4);
      int k  = idx & 15;
      int node = n0 + rr; if (node >= NN) node = 0;
      const float* p = aggx + (size_t)node * DD + k * 8;
      f32x4 a = *(const f32x4*)p;
      f32x4 b = *(const f32x4*)(p + 4);
      u16x8 v;
      v[0]=f2bf(a[0]); v[1]=f2bf(a[1]); v[2]=f2bf(a[2]); v[3]=f2bf(a[3]);
      v[4]=f2bf(b[0]); v[5]=f2bf(b[1]); v[6]=f2bf(b[2]); v[7]=f2bf(b[3]);
      *(u16x8*)&As[buf][rr * 128 + ((k ^ (rr & 7)) << 3)] = v;
    }
  };

  auto compute = [&](const u16* AsBuf, const u16* wsrc) {
#pragma unroll
    for (int kk = 0; kk < 4; ++kk) {
      const int k0 = kk * 32 + lkb * 8;
      bf16x8 af[4], bfv[2];
#pragma unroll
      for (int m = 0; m < 4; ++m) {
        int g = m * 16 + lr;
        int slot = kk * 4 + lkb;
        af[m] = *(const bf16x8*)(AsBuf + g * 128 + ((slot ^ (g & 7)) << 3));
      }
#pragma unroll
      for (int n = 0; n < 2; ++n)
        bfv[n] = *(const bf16x8*)(wsrc + ((wc * 32 + n * 16 + lr) << 7) + k0);
#pragma unroll
      for (int m = 0; m < 4; ++m)
#pragma unroll
        for (int n = 0; n < 2; ++n)
          acc[m][n] = __builtin_amdgcn_mfma_f32_16x16x32_bf16(af[m], bfv[n], acc[m][n], 0, 0, 0);
    }
  };

  auto epi_relu = [&](u16* HsBuf, const float* bias) {
#pragma unroll
    for (int n = 0; n < 2; ++n) {
      int colg = wc * 32 + n * 16 + lr;
      float bv = bias[colg];
      int slot = colg >> 3;
#pragma unroll
      for (int m = 0; m < 4; ++m)
#pragma unroll
        for (int r = 0; r < 4; ++r) {
          int rowg = m * 16 + lkb * 4 + r;
          float v = fmaxf(acc[m][n][r] + bv, 0.f);
          HsBuf[rowg * 128 + ((slot ^ (rowg & 7)) << 3) + (colg & 7)] = f2bf(v);
          acc[m][n][r] = 0.f;
        }
    }
  };

  // layer 1: 3 chunks (x | agg | u), 2-phase
  stage_bf(0, 0);
  __syncthreads();
  stage_agg(1);   compute(As[0], w1);               __syncthreads();
  stage_bf(0, 2); compute(As[1], w1 + (1 << 14));   __syncthreads();
                  compute(As[0], w1 + (2 << 14));
  epi_relu(As[1], b1);
  __syncthreads();
  compute(As[1], w2);
  __syncthreads();
  epi_relu(As[0], b2);
  __syncthreads();
  compute(As[0], w3);

  // epilogue 3: x_out overwrites agg rows of this block; node-mean partials
#pragma unroll
  for (int n = 0; n < 2; ++n) {
    int colg = wc * 32 + n * 16 + lr;
    float bias = b3[colg];
#pragma unroll
    for (int m = 0; m < 4; ++m)
#pragma unroll
      for (int r = 0; r < 4; ++r) {
        int rowg = m * 16 + lkb * 4 + r;
        int node = n0 + rowg;
        if (node < NN) {
          float v = acc[m][n][r] + bias;
          aggx[(size_t)node * DD + colg] = v;
          atomicAdd(&red[nbat_s[rowg]][colg], v);
        }
      }
  }
  __syncthreads();
  for (int i = tid; i < NBATCH * 128; i += 256)
    nsumPart[((size_t)blockIdx.x << 10) + i] = (&red[0][0])[i];
}

// ---------------- Global MLP (fp32, tiny) ----------------
__global__ void global_kernel(
    const float* __restrict__ u,
    const float* __restrict__ nsum, const unsigned* __restrict__ ncnt,
    const float* __restrict__ esum, const unsigned* __restrict__ ecnt,
    const float* __restrict__ gW1, const float* __restrict__ gb1,
    const float* __restrict__ gW2, const float* __restrict__ gb2,
    const float* __restrict__ gW3, const float* __restrict__ gb3,
    float* __restrict__ u_out)
{
  __shared__ float gin[NBATCH][384];
  __shared__ float h1[NBATCH][128];
  __shared__ float h2[NBATCH][128];
  int tid = threadIdx.x;
  for (int i = tid; i < NBATCH * 128; i += 256) {
    int r = i >> 7, c = i & 127;
    float nc = (float)(ncnt[r] < 1u ? 1u : ncnt[r]);
    float ec = (float)(ecnt[r] < 1u ? 1u : ecnt[r]);
    gin[r][c] = u[i];
    gin[r][128 + c] = nsum[i] / nc;
    gin[r][256 + c] = esum[i] / ec;
  }
  __syncthreads();
  for (int o = tid; o < NBATCH * 128; o += 256) {
    int r = o >> 7, n = o & 127;
    float s = gb1[n];
    for (int k = 0; k < 384; ++k) s += gin[r][k] * gW1[k * 128 + n];
    h1[r][n] = fmaxf(s, 0.f);
  }
  __syncthreads();
  for (int o = tid; o < NBATCH * 128; o += 256) {
    int r = o >> 7, n = o & 127;
    float s = gb2[n];
    for (int k = 0; k < 128; ++k) s += h1[r][k] * gW2[k * 128 + n];
    h2[r][n] = fmaxf(s, 0.f);
  }
  __syncthreads();
  for (int o = tid; o < NBATCH * 128; o += 256) {
    int r = o >> 7, n = o & 127;
    float s = gb3[n];
    for (int k = 0; k < 128; ++k) s += h2[r][k] * gW3[k * 128 + n];
    u_out[o] = s;
  }
}

extern "C" void kernel_launch(void* const* d_in, const int* in_sizes, int n_in,
                              void* d_out, int out_size, void* d_ws, size_t ws_size,
                              hipStream_t stream) {
  const float* x          = (const float*)d_in[0];
  const int*   edge_index = (const int*)d_in[1];
  const float* edge_attr  = (const float*)d_in[2];
  const float* u          = (const float*)d_in[3];
  const int*   batch      = (const int*)d_in[4];
  const float* eW1 = (const float*)d_in[5];  const float* eb1 = (const float*)d_in[6];
  const float* eW2 = (const float*)d_in[7];  const float* eb2 = (const float*)d_in[8];
  const float* eW3 = (const float*)d_in[9];  const float* eb3 = (const float*)d_in[10];
  const float* nW1 = (const float*)d_in[11]; const float* nb1 = (const float*)d_in[12];
  const float* nW2 = (const float*)d_in[13]; const float* nb2 = (const float*)d_in[14];
  const float* nW3 = (const float*)d_in[15]; const float* nb3 = (const float*)d_in[16];
  const float* gW1 = (const float*)d_in[17]; const float* gb1 = (const float*)d_in[18];
  const float* gW2 = (const float*)d_in[19]; const float* gb2 = (const float*)d_in[20];
  const float* gW3 = (const float*)d_in[21]; const float* gb3 = (const float*)d_in[22];

  float* out      = (float*)d_out;
  float* xout_agg = out;                                  // [NN][128]: agg then x_out
  float* edge_out = out + (size_t)NN * DD;                // [NE][128]
  float* u_out    = out + (size_t)(NN + NE) * DD;         // [8][128]

  char* ws = (char*)d_ws;
  u16* wE1t = (u16*)(ws + 0);         // 131072
  u16* wE2t = (u16*)(ws + 131072);    // 32768
  u16* wE3t = (u16*)(ws + 163840);    // 32768
  u16* wN1t = (u16*)(ws + 196608);    // 98304
  u16* wN2t = (u16*)(ws + 294912);    // 32768
  u16* wN3t = (u16*)(ws + 327680);    // 32768
  float*    esum = (float*)(ws + 360448);     // 4096
  float*    nsum = (float*)(ws + 364544);     // 4096
  unsigned* ecnt = (unsigned*)(ws + 368640);  // 32
  unsigned* ncnt = (unsigned*)(ws + 368672);  // 32
  u16*      ubf  = (u16*)(ws + 369664);       // 2048
  u16*      xbf  = (u16*)(ws + 393216);       // 12,800,000 -> ends 13,193,216
  float* esumPart = (float*)(ws + 13193216);  // 6250*4096 = 25,600,000 -> 38,793,216
  float* nsumPart = (float*)(ws + 38793216);  // 782*4096  =  3,203,072 -> ends 41,996,288

  const int NODE_BLOCKS = (NN + 63) / 64;     // 782
  const int EDGE_BLOCKS = NE / 64;            // 6250

  // zero esum/nsum/ecnt/ncnt (must precede prep's histograms; separate dispatch for ordering)
  hipMemsetAsync(ws + 360448, 0, 8288, stream);

  prep_kernel<<<14964, 256, 0, stream>>>(
      eW1, eW2, eW3, nW1, nW2, nW3,
      wE1t, wE2t, wE3t, wN1t, wN2t, wN3t,
      x, xbf, u, ubf, batch, ncnt, edge_index, ecnt,
      xout_agg);

  edge_kernel<<<EDGE_BLOCKS, 256, 0, stream>>>(
      xbf, edge_attr, ubf, edge_index, batch,
      wE1t, wE2t, wE3t, eb1, eb2, eb3,
      edge_out, xout_agg, esumPart);

  partred_kernel<<<(EDGE_BLOCKS + PR_SPAN - 1) / PR_SPAN, 256, 0, stream>>>(esumPart, esum, EDGE_BLOCKS);

  node_kernel<<<NODE_BLOCKS, 256, 0, stream>>>(
      xbf, xout_agg, ubf, batch,
      wN1t, wN2t, wN3t, nb1, nb2, nb3,
      nsumPart);

  partred_kernel<<<(NODE_BLOCKS + PR_SPAN - 1) / PR_SPAN, 256, 0, stream>>>(nsumPart, nsum, NODE_BLOCKS);

  global_kernel<<<1, 256, 0, stream>>>(
      u, nsum, ncnt, esum, ecnt,
      gW1, gb1, gW2, gb2, gW3, gb3, u_out);
}